// Round 8
// baseline (69.065 us; speedup 1.0000x reference)
//
#include <hip/hip_runtime.h>

// HONU order-3 via MFMA:
//   out[b] = sum_p xb[b,i0(p)]*xb[b,i1(p)] * S[b,p],  S = Xb @ Wexp^T,
//   Wexp[p,k] = w(i0,i1,k) for k in [i1,128], else 0 (banded, ~27% dense).
// comb_idx input ignored (lex order -> analytic weight index).
//
// Measurement model (fits R12-R16 within noise):
//   dur_us = 41 (harness 256MiB ws re-poison fill @6.5TB/s)
//          + ~23 (fixed harness tax: graph replay/sync + post-fill flush)
//          + sum(our kernels).
// R15 removed 11.5us atomic fan-in; R16 collapsed to 2 kernels (~4.4us total).
// R17: merge fused2's two serialized cold-miss latency windows. The fill
// thrashes L2+LLC, so x-stage and w-pack each paid a full HBM-latency round,
// separated by a barrier (pack needed dec). Now every pack thread computes its
// own dpair/mbase (~100 VALU cyc, hidden under the in-flight x loads) so the
// w loads issue in the SAME latency window as the x loads; one barrier total.
// p<NPAIR guarded explicitly (computed dpair is garbage past NPAIR).
//
// R18/R19: identical to R17 — rounds 6 and 7 were infra failures (container
// failed twice / GPU acquisition timeout); the kernel never ran. Resubmitting.

#define NF      129
#define NCOMB   366145
#define NPAIR   8385            // pairs i0<=i1
#define NT      4               // 16-pair tiles per block (64 pairs)
#define NCHUNK  132             // 132*64 = 8448 >= NPAIR
#define NKS     4               // k-steps cover k=0..127; k=128 in epilogue
#define NPW     132             // partials per row (one per bx chunk)

typedef short bf16x8 __attribute__((ext_vector_type(8)));
typedef float f32x4  __attribute__((ext_vector_type(4)));

union i4b8 { int4 i; bf16x8 b; };

static __device__ inline unsigned bfpack2(float lo, float hi) {
    union { float f; unsigned u; } a, b; a.f = lo; b.f = hi;
    return ((b.u + 0x8000u) & 0xffff0000u) | ((a.u + 0x8000u) >> 16);
}

static __device__ inline void dpair(int p, int& i0, int& i1) {
    int t = (int)((259.0f - sqrtf((float)(67081 - 8 * p))) * 0.5f);
    t = t < 0 ? 0 : (t > 128 ? 128 : t);
    while (t < 128 && ((t + 1) * (258 - t)) / 2 <= p) ++t;
    while (t > 0   && (t * (259 - t)) / 2      >  p) --t;
    i0 = t; i1 = t + (p - (t * (259 - t)) / 2);
}

static __device__ inline int mbase(int i0, int i1) {
    const int n0 = NF - i0, n1 = NF - i1;
    return NCOMB - (n0 * (n0 + 1) * (n0 + 2)) / 6
                 + ((n0 * (n0 + 1)) >> 1) - ((n1 * (n1 + 1)) >> 1);
}

// ---- fused: one block per 64-pair chunk, full 256-row batch in LDS ----
__global__ __launch_bounds__(1024, 1) void honu_fused3(const float* __restrict__ x,
                                                       const float* __restrict__ w,
                                                       float* __restrict__ part) {
    __shared__ float  xf[256 * NF];         // 132,096 B: [row][feat], feat0 = bias
    __shared__ bf16x8 wls[NT * NKS * 64];   //  16,384 B: B-frags [(nt*4+s)*64+lane]
    __shared__ int2   dec[64];              //     512 B: {i0|i1<<16, bits(wlast)}

    const int tid  = threadIdx.x;
    const int lane = tid & 63;
    const int wv   = tid >> 6;              // 16 waves: wave = 16-row M-slice
    const int bx   = blockIdx.x;            // pair chunk (64 pairs)

    // ======== Phase 1: ONE latency window (x loads + w loads overlapped) ====
    // x-tile loads issue first (8 independent float4 per thread)
    const int r = tid >> 2, q = tid & 3;
    const float4* xr = (const float4*)(x + (size_t)r * 128);
    float4 xv[8];
    #pragma unroll
    for (int t = 0; t < 8; ++t) xv[t] = xr[q + 4 * t];

    // per-thread pair decode (VALU, hides under the x-load latency)
    const int pl = tid >> 4, rr = tid & 15;  // pack item = pair pl, 8-k run rr
    const int p  = bx * 64 + pl;
    int i0 = 0, i1 = 200, mb = 0;            // i1=200: invalid sentinel
    if (p < NPAIR) { dpair(p, i0, i1); mb = mbase(i0, i1); }

    // w loads for this thread's run issue in the SAME window as the x loads
    const int k0 = rr * 8;
    int4 vout = make_int4(0, 0, 0, 0);
    if (p < NPAIR && k0 + 7 >= i1) {         // run intersects band
        float f[8];
        #pragma unroll
        for (int j = 0; j < 8; ++j) {
            const int k = k0 + j;
            int off = k - i1; off = off < 0 ? 0 : off;
            const float t = w[mb + off];     // contiguous within pair
            f[j] = (k >= i1) ? t : 0.0f;
        }
        vout.x = (int)bfpack2(f[0], f[1]);
        vout.y = (int)bfpack2(f[2], f[3]);
        vout.z = (int)bfpack2(f[4], f[5]);
        vout.w = (int)bfpack2(f[6], f[7]);
    }

    // dec for the epilogue (+wlast @k=128), one thread per pair
    if (rr == 0) {
        unsigned wl = 0;
        if (p < NPAIR) {
            union { float f; unsigned u; } c; c.f = w[mb + 128 - i1];
            wl = c.u;
        }
        dec[pl] = make_int2(i0 | (i1 << 16), (int)wl);
    }

    // LDS writes: B-frag image + x-tile + bias col
    {
        const int nt = pl >> 4, s = rr >> 2;
        const int slane = ((rr & 3) << 4) | (pl & 15);
        ((int4*)wls)[(nt * NKS + s) * 64 + slane] = vout;   // ds_write_b128
    }
    {
        float* d = &xf[r * NF + 1];
        #pragma unroll
        for (int t = 0; t < 8; ++t) {
            const int c4 = q + 4 * t;
            float* dd = d + 4 * c4;
            dd[0] = xv[t].x; dd[1] = xv[t].y; dd[2] = xv[t].z; dd[3] = xv[t].w;
        }
    }
    if (tid < 256) xf[tid * NF] = 1.0f;
    __syncthreads();                         // the ONLY barrier

    // ======== Phase 2: A-frags, MFMA, fused fp32 epilogue, partial store ====
    const int am = wv * 16 + (lane & 15);
    const int aq = (lane >> 4) * 8;
    const float* xa = &xf[am * NF + aq];
    bf16x8 a[NKS];
    #pragma unroll
    for (int s = 0; s < NKS; ++s) {
        const float* pp = xa + s * 32;
        i4b8 av;
        av.i.x = (int)bfpack2(pp[0], pp[1]);
        av.i.y = (int)bfpack2(pp[2], pp[3]);
        av.i.z = (int)bfpack2(pp[4], pp[5]);
        av.i.w = (int)bfpack2(pp[6], pp[7]);
        a[s] = av.b;
    }

    const int lr0 = wv * 16 + (lane >> 4) * 4;   // row base of C rows (0..255)
    const float* r0 = &xf[lr0 * NF];
    float o0 = 0.f, o1 = 0.f, o2 = 0.f, o3 = 0.f;

    #pragma unroll
    for (int nt = 0; nt < NT; ++nt) {
        f32x4 acc = {0.f, 0.f, 0.f, 0.f};
        #pragma unroll
        for (int s = 0; s < NKS; ++s)
            acc = __builtin_amdgcn_mfma_f32_16x16x32_bf16(
                      a[s], wls[(nt * NKS + s) * 64 + lane], acc, 0, 0, 0);

        const int2 pd = dec[nt * 16 + (lane & 15)];
        const int e0 = pd.x & 0xffff;
        int e1 = pd.x >> 16; if (e1 > 128) e1 = 0;   // invalid pair: wl=0, acc=0
        union { int i; float f; } wc; wc.i = pd.y;
        const float wl = wc.f;                        // k=128 column, fp32
        o0 = fmaf(acc[0] + r0[128]          * wl, r0[e0]          * r0[e1],          o0);
        o1 = fmaf(acc[1] + r0[NF + 128]     * wl, r0[NF + e0]     * r0[NF + e1],     o1);
        o2 = fmaf(acc[2] + r0[2 * NF + 128] * wl, r0[2 * NF + e0] * r0[2 * NF + e1], o2);
        o3 = fmaf(acc[3] + r0[3 * NF + 128] * wl, r0[3 * NF + e0] * r0[3 * NF + e1], o3);
    }

    // reduce over 16 cols per quad, then ONE disjoint store per row (no atomics)
    #pragma unroll
    for (int msk = 1; msk < 16; msk <<= 1) {
        o0 += __shfl_xor(o0, msk);
        o1 += __shfl_xor(o1, msk);
        o2 += __shfl_xor(o2, msk);
        o3 += __shfl_xor(o3, msk);
    }
    if ((lane & 15) == 0) {
        float* pp = part + (size_t)lr0 * NPW + bx;
        pp[0]       = o0;
        pp[NPW]     = o1;
        pp[2 * NPW] = o2;
        pp[3 * NPW] = o3;
    }
}

// ---- final reduce: one wave per output row, coalesced, writes out ----
__global__ __launch_bounds__(256) void honu_reduce(const float* __restrict__ part,
                                                   float* __restrict__ out) {
    const int lane = threadIdx.x & 63;
    const int r = blockIdx.x * 4 + (threadIdx.x >> 6);
    const float* pr = part + (size_t)r * NPW;
    float s = pr[lane] + pr[64 + lane] + (lane < 4 ? pr[128 + lane] : 0.f);
    #pragma unroll
    for (int m = 32; m >= 1; m >>= 1) s += __shfl_xor(s, m);
    if (lane == 0) out[r] = s;
}

extern "C" void kernel_launch(void* const* d_in, const int* in_sizes, int n_in,
                              void* d_out, int out_size, void* d_ws, size_t ws_size,
                              hipStream_t stream) {
    const float* x      = (const float*)d_in[0];
    const float* weight = (const float*)d_in[1];
    // d_in[2] (comb_idx) unused: lex order computed analytically.
    float* out  = (float*)d_out;
    float* part = (float*)d_ws;             // 135 KB partials [row][bx]

    honu_fused3<<<NCHUNK, 1024, 0, stream>>>(x, weight, part);
    honu_reduce<<<64, 256, 0, stream>>>(part, out);
}